// Round 2
// baseline (489.007 us; speedup 1.0000x reference)
//
#include <hip/hip_runtime.h>

typedef __attribute__((ext_vector_type(8))) __bf16 bf16x8;
typedef __attribute__((ext_vector_type(4))) float f32x4;

#define N_ 1024
#define C_ 64
#define BP_ 48

static __device__ __forceinline__ unsigned short f2bf(float f) {
    __bf16 b = (__bf16)f;
    return __builtin_bit_cast(unsigned short, b);
}
static __device__ __forceinline__ unsigned int pack2(float a, float b) {
    return (unsigned int)f2bf(a) | ((unsigned int)f2bf(b) << 16);
}
// order-preserving float<->uint encoding for atomicMax on floats of any sign
static __device__ __forceinline__ unsigned int fenc(float f) {
    unsigned int b = __builtin_bit_cast(unsigned int, f);
    return (b & 0x80000000u) ? ~b : (b | 0x80000000u);
}
static __device__ __forceinline__ float fdec(unsigned int u) {
    unsigned int b = (u & 0x80000000u) ? (u & 0x7fffffffu) : ~u;
    return __builtin_bit_cast(float, b);
}

// ---------------------------------------------------------------------------
// K1: v1/v2 fold of W_emb, s1/s2 per node, per-bp max(s2) (atomic), and bf16
// transpose xT[bp][c][j].  grid (16 j-tiles, 48 bp), block 256 (4 waves).
// ---------------------------------------------------------------------------
__global__ __launch_bounds__(256) void gat_pre(
    const float* __restrict__ x, const float* __restrict__ Wemb,
    const float* __restrict__ a1, const float* __restrict__ a2,
    float* __restrict__ s1g, float* __restrict__ s2g,
    unsigned short* __restrict__ xT, unsigned int* __restrict__ M2enc)
{
    __shared__ float xs[64][65];
    const int t = threadIdx.x, l = t & 63, w = t >> 6;
    const int j0 = blockIdx.x * 64;
    const int bp = blockIdx.y;

    // v1[c]=sum_h a1[h]*W_emb[h][c] for c = lane (x_emb folds away)
    float v1 = 0.f, v2 = 0.f;
    #pragma unroll 8
    for (int h = 0; h < 64; ++h) {
        float we = Wemb[h * 64 + l];
        v1 = fmaf(a1[h], we, v1);
        v2 = fmaf(a2[h], we, v2);
    }
    const float* xb = x + ((size_t)bp * N_ + j0) * C_;
    float wmax = -1e30f;
    #pragma unroll
    for (int it = 0; it < 16; ++it) {
        int j = it * 4 + w;                 // wave w handles rows w,4+w,...
        float xv = xb[j * C_ + l];          // coalesced 256B
        xs[j][l] = xv;
        float p1 = xv * v1, p2 = xv * v2;
        #pragma unroll
        for (int off = 32; off >= 1; off >>= 1) {
            p1 += __shfl_xor(p1, off);
            p2 += __shfl_xor(p2, off);
        }
        if (l == 0) {
            s1g[bp * N_ + j0 + j] = p1;
            s2g[bp * N_ + j0 + j] = p2;
        }
        wmax = fmaxf(wmax, p2);             // all lanes hold reduced p2
    }
    if (l == 0) atomicMax(M2enc + bp, fenc(wmax));
    __syncthreads();
    // transpose out: thread t handles c = t>>2, 16 j's
    const int c = t >> 2, part = t & 3;
    unsigned int ow[8];
    #pragma unroll
    for (int k = 0; k < 16; k += 2) {
        unsigned int lo = f2bf(xs[part * 16 + k][c]);
        unsigned int hi = f2bf(xs[part * 16 + k + 1][c]);
        ow[k >> 1] = lo | (hi << 16);
    }
    uint4* dst = (uint4*)(xT + (size_t)bp * C_ * N_ + (size_t)c * N_ + j0 + part * 16);
    dst[0] = make_uint4(ow[0], ow[1], ow[2], ow[3]);
    dst[1] = make_uint4(ow[4], ow[5], ow[6], ow[7]);
}

// ---------------------------------------------------------------------------
// K2: fused masked-softmax attention + aggregation + output linear + sigmoid.
// Fixed softmax shift m_i = leaky(s1_i + max_j s2_j) -> chunks independent,
// no online rescale, no per-chunk reductions (l-sum deferred to one butterfly).
// grid (64 i-tiles of 16, 48 bp), block 128 = 2 independent waves x 8 rows.
// 6144 waves = 24/CU for latency hiding.  No __syncthreads anywhere.
// ---------------------------------------------------------------------------
__global__ __launch_bounds__(128, 6) void gat_main(
    const float* __restrict__ Ag, const unsigned short* __restrict__ xT,
    const float* __restrict__ s1g, const float* __restrict__ s2g,
    const unsigned int* __restrict__ M2enc,
    const float* __restrict__ Wlin, float* __restrict__ out,
    float* __restrict__ outA)
{
    // per-wave P tile: 8 rows x 256 j bf16, row stride 264 ushort (8 pad)
    __shared__ unsigned short Plds[2][8][264];
    const int l = threadIdx.x & 63, w = threadIdx.x >> 6;
    const int i15 = l & 15, q = l >> 4;
    const int bp = blockIdx.y;
    const int ibase = blockIdx.x * 16 + w * 8;   // 8 rows per wave

    const float M2 = fdec(M2enc[bp]);
    const float s1_l = s1g[bp * N_ + ibase + (l & 7)];  // lane r holds s1 of row r
    const float zr = s1_l + M2;
    const float m_l = fmaxf(zr, 0.01f * zr);            // fixed softmax shift

    const float* Arow = Ag + (size_t)bp * N_ * N_ + (size_t)ibase * N_;
    float* oArow = outA + (size_t)bp * N_ * N_ + (size_t)ibase * N_;
    const unsigned short* xTb = xT + (size_t)bp * C_ * N_;

    f32x4 acc[4] = {};                 // rows q*4+r (q<2 real), c = nt*16+i15
    float lsum[8] = {0.f,0.f,0.f,0.f,0.f,0.f,0.f,0.f};

    for (int jc = 0; jc < 4; ++jc) {
        const int j0c = jc * 256;
        const f32x4 s2p = *(const f32x4*)&s2g[bp * N_ + j0c + 4 * l];
        #pragma unroll
        for (int h = 0; h < 2; ++h) {
            f32x4 Ap[4];
            #pragma unroll
            for (int r4 = 0; r4 < 4; ++r4)   // prefetch 4 HBM A-rows (float4)
                Ap[r4] = *(const f32x4*)&Arow[(size_t)(h * 4 + r4) * N_ + j0c + 4 * l];
            #pragma unroll
            for (int r4 = 0; r4 < 4; ++r4) {
                const int rr = h * 4 + r4;
                *(f32x4*)&oArow[(size_t)rr * N_ + j0c + 4 * l] = Ap[r4];  // A passthrough
                float s1i = __shfl(s1_l, rr);
                float mi  = __shfl(m_l, rr);
                float e[4];
                #pragma unroll
                for (int k = 0; k < 4; ++k) {
                    float zz = s1i + s2p[k];
                    zz = fmaxf(zz, 0.01f * zz);                  // leaky_relu
                    e[k] = (Ap[r4][k] != 0.f) ? __expf(zz - mi) : 0.f;
                }
                lsum[rr] += (e[0] + e[1]) + (e[2] + e[3]);       // per-lane partial
                *(uint2*)&Plds[w][rr][4 * l] =
                    make_uint2(pack2(e[0], e[1]), pack2(e[2], e[3]));
            }
        }
        // acc += P_chunk @ X_chunk   (M16(8 real) x N64 x K256 per wave)
        #pragma unroll
        for (int s = 0; s < 8; ++s) {
            bf16x8 af = *(const bf16x8*)&Plds[w][i15 & 7][s * 32 + q * 8];
            #pragma unroll
            for (int nt = 0; nt < 4; ++nt) {
                bf16x8 bfr = *(const bf16x8*)&xTb[(size_t)(nt * 16 + i15) * N_ +
                                                  j0c + s * 32 + q * 8];
                acc[nt] = __builtin_amdgcn_mfma_f32_16x16x32_bf16(af, bfr, acc[nt], 0, 0, 0);
            }
        }
    }

    // one deferred l-sum reduction per row
    #pragma unroll
    for (int rr = 0; rr < 8; ++rr)
        #pragma unroll
        for (int off = 32; off >= 1; off >>= 1)
            lsum[rr] += __shfl_xor(lsum[rr], off);

    // ---- epilogue: agg = acc/l, LDS round-trip to A-layout, @W_lin^T, sigmoid
    unsigned short* aggl = &Plds[w][0][0];   // reuse own P slice, stride 72
    #pragma unroll
    for (int nt = 0; nt < 4; ++nt)
        #pragma unroll
        for (int r = 0; r < 4; ++r) {
            int row = q * 4 + r;
            if (row < 8)
                aggl[row * 72 + nt * 16 + i15] = f2bf(acc[nt][r] / lsum[row]);
        }
    f32x4 d2[4] = {};
    #pragma unroll
    for (int s = 0; s < 2; ++s) {
        bf16x8 af = *(const bf16x8*)&aggl[(i15 & 7) * 72 + s * 32 + q * 8];
        #pragma unroll
        for (int nt = 0; nt < 4; ++nt) {
            const float* wp = Wlin + (size_t)(nt * 16 + i15) * C_ + s * 32 + q * 8;
            bf16x8 bfr;
            #pragma unroll
            for (int jj = 0; jj < 8; ++jj) bfr[jj] = (__bf16)wp[jj];
            d2[nt] = __builtin_amdgcn_mfma_f32_16x16x32_bf16(af, bfr, d2[nt], 0, 0, 0);
        }
    }
    if (q < 2) {                          // rows 0..7 are real; 8..15 duplicates
        float* orow = out + ((size_t)bp * N_ + ibase) * C_;
        #pragma unroll
        for (int nt = 0; nt < 4; ++nt)
            #pragma unroll
            for (int r = 0; r < 4; ++r)
                orow[(size_t)(q * 4 + r) * C_ + nt * 16 + i15] =
                    1.f / (1.f + __expf(-d2[nt][r]));
    }
}

extern "C" void kernel_launch(void* const* d_in, const int* in_sizes, int n_in,
                              void* d_out, int out_size, void* d_ws, size_t ws_size,
                              hipStream_t stream) {
    const float* x    = (const float*)d_in[0];
    const float* Ag   = (const float*)d_in[1];
    const float* Wemb = (const float*)d_in[2];
    const float* a1   = (const float*)d_in[3];
    const float* a2   = (const float*)d_in[4];
    const float* Wlin = (const float*)d_in[5];
    float* out  = (float*)d_out;
    float* outA = out + (size_t)BP_ * N_ * C_;   // tuple output #2: A passthrough

    float* s1g = (float*)d_ws;                         // 48K f32
    float* s2g = s1g + BP_ * N_;                       // 48K f32
    unsigned int* M2enc = (unsigned int*)(s2g + BP_ * N_);   // 48 u32
    unsigned short* xT = (unsigned short*)(M2enc + BP_);     // 48*64*1024 bf16

    hipMemsetAsync(M2enc, 0, BP_ * sizeof(unsigned int), stream);  // -inf encoded
    gat_pre<<<dim3(16, BP_), dim3(256), 0, stream>>>(x, Wemb, a1, a2,
                                                     s1g, s2g, xT, M2enc);
    gat_main<<<dim3(64, BP_), dim3(128), 0, stream>>>(Ag, xT, s1g, s2g, M2enc,
                                                      Wlin, out, outA);
}

// Round 3
// 471.100 us; speedup vs baseline: 1.0380x; 1.0380x over previous
//
#include <hip/hip_runtime.h>

typedef __attribute__((ext_vector_type(8))) __bf16 bf16x8;
typedef __attribute__((ext_vector_type(4))) float f32x4;

#define N_ 1024
#define C_ 64
#define BP_ 48

static __device__ __forceinline__ unsigned short f2bf(float f) {
    __bf16 b = (__bf16)f;
    return __builtin_bit_cast(unsigned short, b);
}
static __device__ __forceinline__ unsigned int pack2(float a, float b) {
    return (unsigned int)f2bf(a) | ((unsigned int)f2bf(b) << 16);
}
// order-preserving float<->uint encoding for atomicMax on floats of any sign
static __device__ __forceinline__ unsigned int fenc(float f) {
    unsigned int b = __builtin_bit_cast(unsigned int, f);
    return (b & 0x80000000u) ? ~b : (b | 0x80000000u);
}
static __device__ __forceinline__ float fdec(unsigned int u) {
    unsigned int b = (u & 0x80000000u) ? (u & 0x7fffffffu) : ~u;
    return __builtin_bit_cast(float, b);
}

// ---------------------------------------------------------------------------
// K0: pure-streaming A -> outA copy + nibble mask (1 byte per 4 j's).
// No dependent tail -> high outstanding-load duty cycle -> near-peak HBM BW.
// 4096 blocks x 256 thr, exactly 12 float4s per thread.
// ---------------------------------------------------------------------------
__global__ __launch_bounds__(256) void a_copy_mask(
    const f32x4* __restrict__ A4, f32x4* __restrict__ oA4,
    unsigned char* __restrict__ mb)
{
    const int tid = blockIdx.x * 256 + threadIdx.x;
    #pragma unroll 4
    for (int it = 0; it < 12; ++it) {
        const int i = it * (4096 * 256) + tid;
        f32x4 v = A4[i];
        oA4[i] = v;
        mb[i] = (unsigned char)((v[0] != 0.f ? 1 : 0) | (v[1] != 0.f ? 2 : 0) |
                                (v[2] != 0.f ? 4 : 0) | (v[3] != 0.f ? 8 : 0));
    }
}

// ---------------------------------------------------------------------------
// K1: v1/v2 fold of W_emb, s1/s2 per node, per-bp max(s2) (atomic), and bf16
// transpose xT[bp][c][j].  grid (16 j-tiles, 48 bp), block 256 (4 waves).
// ---------------------------------------------------------------------------
__global__ __launch_bounds__(256) void gat_pre(
    const float* __restrict__ x, const float* __restrict__ Wemb,
    const float* __restrict__ a1, const float* __restrict__ a2,
    float* __restrict__ s1g, float* __restrict__ s2g,
    unsigned short* __restrict__ xT, unsigned int* __restrict__ M2enc)
{
    __shared__ float xs[64][65];
    const int t = threadIdx.x, l = t & 63, w = t >> 6;
    const int j0 = blockIdx.x * 64;
    const int bp = blockIdx.y;

    float v1 = 0.f, v2 = 0.f;
    #pragma unroll 8
    for (int h = 0; h < 64; ++h) {
        float we = Wemb[h * 64 + l];
        v1 = fmaf(a1[h], we, v1);
        v2 = fmaf(a2[h], we, v2);
    }
    const float* xb = x + ((size_t)bp * N_ + j0) * C_;
    float wmax = -1e30f;
    #pragma unroll
    for (int it = 0; it < 16; ++it) {
        int j = it * 4 + w;
        float xv = xb[j * C_ + l];
        xs[j][l] = xv;
        float p1 = xv * v1, p2 = xv * v2;
        #pragma unroll
        for (int off = 32; off >= 1; off >>= 1) {
            p1 += __shfl_xor(p1, off);
            p2 += __shfl_xor(p2, off);
        }
        if (l == 0) {
            s1g[bp * N_ + j0 + j] = p1;
            s2g[bp * N_ + j0 + j] = p2;
        }
        wmax = fmaxf(wmax, p2);
    }
    if (l == 0) atomicMax(M2enc + bp, fenc(wmax));
    __syncthreads();
    const int c = t >> 2, part = t & 3;
    unsigned int ow[8];
    #pragma unroll
    for (int k = 0; k < 16; k += 2) {
        unsigned int lo = f2bf(xs[part * 16 + k][c]);
        unsigned int hi = f2bf(xs[part * 16 + k + 1][c]);
        ow[k >> 1] = lo | (hi << 16);
    }
    uint4* dst = (uint4*)(xT + (size_t)bp * C_ * N_ + (size_t)c * N_ + j0 + part * 16);
    dst[0] = make_uint4(ow[0], ow[1], ow[2], ow[3]);
    dst[1] = make_uint4(ow[4], ow[5], ow[6], ow[7]);
}

// ---------------------------------------------------------------------------
// K2: compute kernel — HBM-light (reads mask bytes, not A).
// grid (16 i-tiles, 48 bp), block 256 = 4 independent waves x 16 rows.
// Fixed softmax shift (no online rescale); per-row constants hoisted;
// P -> LDS bf16 -> MFMA 16x16x32 vs xT B-frags from global (L2-hot).
// No __syncthreads anywhere (per-wave LDS slices).
// ---------------------------------------------------------------------------
__global__ __launch_bounds__(256) void gat_compute(
    const unsigned char* __restrict__ maskb, const unsigned short* __restrict__ xT,
    const float* __restrict__ s1g, const float* __restrict__ s2g,
    const unsigned int* __restrict__ M2enc,
    const float* __restrict__ Wlin, float* __restrict__ out)
{
    // per-wave P tile: 16 rows x 256 j bf16, row stride 264 ushort (8 pad)
    __shared__ unsigned short Plds[4][16][264];
    const int l = threadIdx.x & 63, w = threadIdx.x >> 6;
    const int i15 = l & 15, q = l >> 4;
    const int bp = blockIdx.y;
    const int ibase = blockIdx.x * 64 + w * 16;

    const float M2 = fdec(M2enc[bp]);
    const float s1_l = s1g[bp * N_ + ibase + i15];   // lane rr holds s1 of row rr
    const float zr = s1_l + M2;
    const float m_l = fmaxf(zr, 0.01f * zr);         // fixed softmax shift

    // hoist per-row constants out of the chunk loop (16 shuffles total)
    float s1r[16], mr[16];
    #pragma unroll
    for (int rr = 0; rr < 16; ++rr) {
        s1r[rr] = __shfl(s1_l, rr);
        mr[rr]  = __shfl(m_l, rr);
    }

    const unsigned char* mrow = maskb + ((size_t)bp * N_ + ibase) * (N_ / 4);
    const unsigned short* xTb = xT + (size_t)bp * C_ * N_;

    f32x4 acc[4] = {};                 // rows q*4+r, c = nt*16+i15
    float lsum[16];
    #pragma unroll
    for (int rr = 0; rr < 16; ++rr) lsum[rr] = 0.f;

    for (int jc = 0; jc < 4; ++jc) {
        const int j0c = jc * 256;
        const f32x4 s2p = *(const f32x4*)&s2g[bp * N_ + j0c + 4 * l];
        #pragma unroll
        for (int rr = 0; rr < 16; ++rr) {
            unsigned int mb = mrow[(size_t)rr * (N_ / 4) + (j0c >> 2) + l];
            float e[4];
            #pragma unroll
            for (int k = 0; k < 4; ++k) {
                float zz = s1r[rr] + s2p[k];
                zz = fmaxf(zz, 0.01f * zz);                  // leaky_relu
                e[k] = ((mb >> k) & 1u) ? __expf(zz - mr[rr]) : 0.f;
            }
            lsum[rr] += (e[0] + e[1]) + (e[2] + e[3]);
            *(uint2*)&Plds[w][rr][4 * l] =
                make_uint2(pack2(e[0], e[1]), pack2(e[2], e[3]));
        }
        // acc += P_chunk @ X_chunk   (M16 x N64 x K256 per wave)
        #pragma unroll
        for (int s = 0; s < 8; ++s) {
            bf16x8 af = *(const bf16x8*)&Plds[w][i15][s * 32 + q * 8];
            #pragma unroll
            for (int nt = 0; nt < 4; ++nt) {
                bf16x8 bfr = *(const bf16x8*)&xTb[(size_t)(nt * 16 + i15) * N_ +
                                                  j0c + s * 32 + q * 8];
                acc[nt] = __builtin_amdgcn_mfma_f32_16x16x32_bf16(af, bfr, acc[nt], 0, 0, 0);
            }
        }
    }

    // one deferred l-sum reduction per row (16 independent chains)
    #pragma unroll
    for (int rr = 0; rr < 16; ++rr)
        #pragma unroll
        for (int off = 32; off >= 1; off >>= 1)
            lsum[rr] += __shfl_xor(lsum[rr], off);

    // ---- epilogue: agg = acc/l, LDS round-trip to A-layout, @W_lin^T, sigmoid
    unsigned short* aggl = &Plds[w][0][0];   // reuse own P slice, stride 72
    #pragma unroll
    for (int nt = 0; nt < 4; ++nt)
        #pragma unroll
        for (int r = 0; r < 4; ++r) {
            int row = q * 4 + r;
            aggl[row * 72 + nt * 16 + i15] = f2bf(acc[nt][r] / lsum[row]);
        }
    f32x4 d2[4] = {};
    #pragma unroll
    for (int s = 0; s < 2; ++s) {
        bf16x8 af = *(const bf16x8*)&aggl[i15 * 72 + s * 32 + q * 8];
        #pragma unroll
        for (int nt = 0; nt < 4; ++nt) {
            const float* wp = Wlin + (size_t)(nt * 16 + i15) * C_ + s * 32 + q * 8;
            f32x4 w0 = *(const f32x4*)wp;
            f32x4 w1 = *(const f32x4*)(wp + 4);
            bf16x8 bfr;
            #pragma unroll
            for (int jj = 0; jj < 4; ++jj) { bfr[jj] = (__bf16)w0[jj]; bfr[4 + jj] = (__bf16)w1[jj]; }
            d2[nt] = __builtin_amdgcn_mfma_f32_16x16x32_bf16(af, bfr, d2[nt], 0, 0, 0);
        }
    }
    float* orow = out + ((size_t)bp * N_ + ibase) * C_;
    #pragma unroll
    for (int nt = 0; nt < 4; ++nt)
        #pragma unroll
        for (int r = 0; r < 4; ++r)
            orow[(size_t)(q * 4 + r) * C_ + nt * 16 + i15] =
                1.f / (1.f + __expf(-d2[nt][r]));
}

extern "C" void kernel_launch(void* const* d_in, const int* in_sizes, int n_in,
                              void* d_out, int out_size, void* d_ws, size_t ws_size,
                              hipStream_t stream) {
    const float* x    = (const float*)d_in[0];
    const float* Ag   = (const float*)d_in[1];
    const float* Wemb = (const float*)d_in[2];
    const float* a1   = (const float*)d_in[3];
    const float* a2   = (const float*)d_in[4];
    const float* Wlin = (const float*)d_in[5];
    float* out  = (float*)d_out;
    float* outA = out + (size_t)BP_ * N_ * C_;   // tuple output #2: A passthrough

    // ws layout (~19.3 MB total)
    float* s1g = (float*)d_ws;                               // 48K f32
    float* s2g = s1g + BP_ * N_;                             // 48K f32
    unsigned int* M2enc = (unsigned int*)(s2g + BP_ * N_);   // 48 u32 (+pad)
    unsigned short* xT = (unsigned short*)(M2enc + 64);      // 48*64*1024 bf16 (6.3MB)
    unsigned char* maskb = (unsigned char*)(xT + (size_t)BP_ * C_ * N_); // 12.6MB

    hipMemsetAsync(M2enc, 0, 64 * sizeof(unsigned int), stream);
    a_copy_mask<<<dim3(4096), dim3(256), 0, stream>>>(
        (const f32x4*)Ag, (f32x4*)outA, maskb);
    gat_pre<<<dim3(16, BP_), dim3(256), 0, stream>>>(x, Wemb, a1, a2,
                                                     s1g, s2g, xT, M2enc);
    gat_compute<<<dim3(16, BP_), dim3(256), 0, stream>>>(maskb, xT, s1g, s2g,
                                                         M2enc, Wlin, out);
}

// Round 4
// 431.833 us; speedup vs baseline: 1.1324x; 1.0909x over previous
//
#include <hip/hip_runtime.h>

typedef __attribute__((ext_vector_type(8))) __bf16 bf16x8;
typedef __attribute__((ext_vector_type(4))) float f32x4;

#define N_ 1024
#define C_ 64
#define BP_ 48

static __device__ __forceinline__ unsigned short f2bf(float f) {
    __bf16 b = (__bf16)f;
    return __builtin_bit_cast(unsigned short, b);
}
static __device__ __forceinline__ unsigned int pack2(float a, float b) {
    return (unsigned int)f2bf(a) | ((unsigned int)f2bf(b) << 16);
}

// ---------------------------------------------------------------------------
// K0: pure-streaming A -> outA copy + nibble mask (1 byte per 4 j's).
// Non-temporal on the 403MB A stream (zero reuse; keep L2 for xT/mask).
// 4096 blocks x 256 thr, exactly 12 float4s per thread.  Proven ceiling for
// this pattern: rocclr fill = 6.6 TB/s.
// ---------------------------------------------------------------------------
__global__ __launch_bounds__(256) void a_copy_mask(
    const f32x4* __restrict__ A4, f32x4* __restrict__ oA4,
    unsigned char* __restrict__ mb)
{
    const int tid = blockIdx.x * 256 + threadIdx.x;
    #pragma unroll 4
    for (int it = 0; it < 12; ++it) {
        const int i = it * (4096 * 256) + tid;
        f32x4 v = __builtin_nontemporal_load(&A4[i]);
        __builtin_nontemporal_store(v, &oA4[i]);
        mb[i] = (unsigned char)((v[0] != 0.f ? 1 : 0) | (v[1] != 0.f ? 2 : 0) |
                                (v[2] != 0.f ? 4 : 0) | (v[3] != 0.f ? 8 : 0));
    }
}

// ---------------------------------------------------------------------------
// K1: v1/v2 fold of W_emb, s1/s2 per node, per-wave max(s2) -> M2part, and
// bf16 transpose xT[bp][c][j].  grid (16 j-tiles, 48 bp), block 256 (4 waves).
// s1/s2 via LDS partial dots: thread t owns (row t>>2, channel quarter t&3),
// reduced with 2 shuffles (was: 12 serial shuffles per row).
// ---------------------------------------------------------------------------
__global__ __launch_bounds__(256) void gat_pre(
    const float* __restrict__ x, const float* __restrict__ Wemb,
    const float* __restrict__ a1, const float* __restrict__ a2,
    float* __restrict__ s1g, float* __restrict__ s2g,
    unsigned short* __restrict__ xT, float* __restrict__ M2part)
{
    __shared__ float xs[64][65];
    __shared__ float vs[2][64];
    const int t = threadIdx.x, l = t & 63, w = t >> 6;
    const int j0 = blockIdx.x * 64;
    const int bp = blockIdx.y;

    // wave 0: v1[c]=sum_h a1[h]*W_emb[h][c] (x_emb folds away; lane l = c)
    if (w == 0) {
        float v1 = 0.f, v2 = 0.f;
        #pragma unroll 8
        for (int h = 0; h < 64; ++h) {
            float we = Wemb[h * 64 + l];
            v1 = fmaf(a1[h], we, v1);
            v2 = fmaf(a2[h], we, v2);
        }
        vs[0][l] = v1; vs[1][l] = v2;
    }
    // cooperative x-tile load (coalesced 256B per wave-instr)
    const float* xb = x + ((size_t)bp * N_ + j0) * C_;
    #pragma unroll
    for (int it = 0; it < 16; ++it)
        xs[it * 4 + w][l] = xb[(it * 4 + w) * C_ + l];
    __syncthreads();

    // partial dot: row j = t>>2 (within-wave l>>2), channels c0..c0+15
    const int jr = t >> 2, c0 = (t & 3) * 16;
    float p1 = 0.f, p2 = 0.f;
    #pragma unroll
    for (int k = 0; k < 16; ++k) {
        float xv = xs[jr][c0 + k];
        p1 = fmaf(xv, vs[0][c0 + k], p1);
        p2 = fmaf(xv, vs[1][c0 + k], p2);
    }
    p1 += __shfl_xor(p1, 1); p1 += __shfl_xor(p1, 2);
    p2 += __shfl_xor(p2, 1); p2 += __shfl_xor(p2, 2);
    if ((l & 3) == 0) {
        s1g[bp * N_ + j0 + jr] = p1;
        s2g[bp * N_ + j0 + jr] = p2;
    }
    // wave-wide max of s2 over its 16 rows (quads already uniform)
    float m = p2;
    m = fmaxf(m, __shfl_xor(m, 4));
    m = fmaxf(m, __shfl_xor(m, 8));
    m = fmaxf(m, __shfl_xor(m, 16));
    m = fmaxf(m, __shfl_xor(m, 32));
    if (l == 0) M2part[bp * 64 + blockIdx.x * 4 + w] = m;

    // transpose out: thread t handles c = t>>2, 16 j's (reads pre-sync xs)
    const int c = t >> 2, part = t & 3;
    unsigned int ow[8];
    #pragma unroll
    for (int k = 0; k < 16; k += 2) {
        unsigned int lo = f2bf(xs[part * 16 + k][c]);
        unsigned int hi = f2bf(xs[part * 16 + k + 1][c]);
        ow[k >> 1] = lo | (hi << 16);
    }
    uint4* dst = (uint4*)(xT + (size_t)bp * C_ * N_ + (size_t)c * N_ + j0 + part * 16);
    dst[0] = make_uint4(ow[0], ow[1], ow[2], ow[3]);
    dst[1] = make_uint4(ow[4], ow[5], ow[6], ow[7]);
}

// ---------------------------------------------------------------------------
// K2: compute kernel — HBM-light (reads mask bytes, not A).
// grid (16 i-tiles, 48 bp), block 256 = 4 independent waves x 16 rows.
// Fixed softmax shift m_i = leaky(s1_i + max_j s2_j): chunks independent, no
// online rescale; l-sum deferred to one butterfly.  No __syncthreads.
// ---------------------------------------------------------------------------
__global__ __launch_bounds__(256) void gat_compute(
    const unsigned char* __restrict__ maskb, const unsigned short* __restrict__ xT,
    const float* __restrict__ s1g, const float* __restrict__ s2g,
    const float* __restrict__ M2part,
    const float* __restrict__ Wlin, float* __restrict__ out)
{
    // per-wave P tile: 16 rows x 256 j bf16, row stride 264 ushort (8 pad)
    __shared__ unsigned short Plds[4][16][264];
    const int l = threadIdx.x & 63, w = threadIdx.x >> 6;
    const int i15 = l & 15, q = l >> 4;
    const int bp = blockIdx.y;
    const int ibase = blockIdx.x * 64 + w * 16;

    // reduce per-wave maxima -> M2 (once; 6 shuffles)
    float m2v = M2part[bp * 64 + l];
    #pragma unroll
    for (int off = 32; off >= 1; off >>= 1)
        m2v = fmaxf(m2v, __shfl_xor(m2v, off));
    const float M2 = m2v;

    const float s1_l = s1g[bp * N_ + ibase + i15];   // lane rr holds s1 of row rr
    const float zr = s1_l + M2;
    const float m_l = fmaxf(zr, 0.01f * zr);         // fixed softmax shift

    float s1r[16], mr[16];
    #pragma unroll
    for (int rr = 0; rr < 16; ++rr) {
        s1r[rr] = __shfl(s1_l, rr);
        mr[rr]  = __shfl(m_l, rr);
    }

    const unsigned char* mrow = maskb + ((size_t)bp * N_ + ibase) * (N_ / 4);
    const unsigned short* xTb = xT + (size_t)bp * C_ * N_;

    f32x4 acc[4] = {};                 // rows q*4+r, c = nt*16+i15
    float lsum[16];
    #pragma unroll
    for (int rr = 0; rr < 16; ++rr) lsum[rr] = 0.f;

    for (int jc = 0; jc < 4; ++jc) {
        const int j0c = jc * 256;
        const f32x4 s2p = *(const f32x4*)&s2g[bp * N_ + j0c + 4 * l];
        #pragma unroll
        for (int rr = 0; rr < 16; ++rr) {
            unsigned int mb = mrow[(size_t)rr * (N_ / 4) + (j0c >> 2) + l];
            float e[4];
            #pragma unroll
            for (int k = 0; k < 4; ++k) {
                float zz = s1r[rr] + s2p[k];
                zz = fmaxf(zz, 0.01f * zz);                  // leaky_relu
                e[k] = ((mb >> k) & 1u) ? __expf(zz - mr[rr]) : 0.f;
            }
            lsum[rr] += (e[0] + e[1]) + (e[2] + e[3]);
            *(uint2*)&Plds[w][rr][4 * l] =
                make_uint2(pack2(e[0], e[1]), pack2(e[2], e[3]));
        }
        // acc += P_chunk @ X_chunk   (M16 x N64 x K256 per wave)
        #pragma unroll
        for (int s = 0; s < 8; ++s) {
            bf16x8 af = *(const bf16x8*)&Plds[w][i15][s * 32 + q * 8];
            #pragma unroll
            for (int nt = 0; nt < 4; ++nt) {
                bf16x8 bfr = *(const bf16x8*)&xTb[(size_t)(nt * 16 + i15) * N_ +
                                                  j0c + s * 32 + q * 8];
                acc[nt] = __builtin_amdgcn_mfma_f32_16x16x32_bf16(af, bfr, acc[nt], 0, 0, 0);
            }
        }
    }

    // one deferred l-sum reduction per row (16 independent chains)
    #pragma unroll
    for (int rr = 0; rr < 16; ++rr)
        #pragma unroll
        for (int off = 32; off >= 1; off >>= 1)
            lsum[rr] += __shfl_xor(lsum[rr], off);

    // ---- epilogue: agg = acc/l, LDS round-trip to A-layout, @W_lin^T, sigmoid
    unsigned short* aggl = &Plds[w][0][0];   // reuse own P slice, stride 72
    #pragma unroll
    for (int nt = 0; nt < 4; ++nt)
        #pragma unroll
        for (int r = 0; r < 4; ++r) {
            int row = q * 4 + r;
            aggl[row * 72 + nt * 16 + i15] = f2bf(acc[nt][r] / lsum[row]);
        }
    f32x4 d2[4] = {};
    #pragma unroll
    for (int s = 0; s < 2; ++s) {
        bf16x8 af = *(const bf16x8*)&aggl[i15 * 72 + s * 32 + q * 8];
        #pragma unroll
        for (int nt = 0; nt < 4; ++nt) {
            const float* wp = Wlin + (size_t)(nt * 16 + i15) * C_ + s * 32 + q * 8;
            f32x4 w0 = *(const f32x4*)wp;
            f32x4 w1 = *(const f32x4*)(wp + 4);
            bf16x8 bfr;
            #pragma unroll
            for (int jj = 0; jj < 4; ++jj) { bfr[jj] = (__bf16)w0[jj]; bfr[4 + jj] = (__bf16)w1[jj]; }
            d2[nt] = __builtin_amdgcn_mfma_f32_16x16x32_bf16(af, bfr, d2[nt], 0, 0, 0);
        }
    }
    float* orow = out + ((size_t)bp * N_ + ibase) * C_;
    #pragma unroll
    for (int nt = 0; nt < 4; ++nt)
        #pragma unroll
        for (int r = 0; r < 4; ++r)
            orow[(size_t)(q * 4 + r) * C_ + nt * 16 + i15] =
                1.f / (1.f + __expf(-d2[nt][r]));
}

extern "C" void kernel_launch(void* const* d_in, const int* in_sizes, int n_in,
                              void* d_out, int out_size, void* d_ws, size_t ws_size,
                              hipStream_t stream) {
    const float* x    = (const float*)d_in[0];
    const float* Ag   = (const float*)d_in[1];
    const float* Wemb = (const float*)d_in[2];
    const float* a1   = (const float*)d_in[3];
    const float* a2   = (const float*)d_in[4];
    const float* Wlin = (const float*)d_in[5];
    float* out  = (float*)d_out;
    float* outA = out + (size_t)BP_ * N_ * C_;   // tuple output #2: A passthrough

    // ws layout (~19.3 MB total)
    float* s1g = (float*)d_ws;                               // 48K f32
    float* s2g = s1g + BP_ * N_;                             // 48K f32
    float* M2part = s2g + BP_ * N_;                          // 48*64 f32
    unsigned short* xT = (unsigned short*)(M2part + BP_ * 64);       // 6.3MB bf16
    unsigned char* maskb = (unsigned char*)(xT + (size_t)BP_ * C_ * N_); // 12.6MB

    a_copy_mask<<<dim3(4096), dim3(256), 0, stream>>>(
        (const f32x4*)Ag, (f32x4*)outA, maskb);
    gat_pre<<<dim3(16, BP_), dim3(256), 0, stream>>>(x, Wemb, a1, a2,
                                                     s1g, s2g, xT, M2part);
    gat_compute<<<dim3(16, BP_), dim3(256), 0, stream>>>(maskb, xT, s1g, s2g,
                                                         M2part, Wlin, out);
}

// Round 5
// 409.894 us; speedup vs baseline: 1.1930x; 1.0535x over previous
//
#include <hip/hip_runtime.h>

typedef __attribute__((ext_vector_type(8))) __bf16 bf16x8;
typedef __attribute__((ext_vector_type(4))) float f32x4;

#define N_ 1024
#define C_ 64
#define BP_ 48

static __device__ __forceinline__ unsigned short f2bf(float f) {
    __bf16 b = (__bf16)f;
    return __builtin_bit_cast(unsigned short, b);
}
static __device__ __forceinline__ unsigned int pack2(float a, float b) {
    return (unsigned int)f2bf(a) | ((unsigned int)f2bf(b) << 16);
}

// ---------------------------------------------------------------------------
// K1: v1/v2 fold of W_emb, s1/s2 per node, per-wave max(s2) -> M2part, and
// bf16 transpose xT[bp][c][j].  grid (16 j-tiles, 48 bp), block 256 (4 waves).
// ---------------------------------------------------------------------------
__global__ __launch_bounds__(256) void gat_pre(
    const float* __restrict__ x, const float* __restrict__ Wemb,
    const float* __restrict__ a1, const float* __restrict__ a2,
    float* __restrict__ s1g, float* __restrict__ s2g,
    unsigned short* __restrict__ xT, float* __restrict__ M2part)
{
    __shared__ float xs[64][65];
    __shared__ float vs[2][64];
    const int t = threadIdx.x, l = t & 63, w = t >> 6;
    const int j0 = blockIdx.x * 64;
    const int bp = blockIdx.y;

    if (w == 0) {   // v1[c]=sum_h a1[h]*W_emb[h][c]  (x_emb folds away)
        float v1 = 0.f, v2 = 0.f;
        #pragma unroll 8
        for (int h = 0; h < 64; ++h) {
            float we = Wemb[h * 64 + l];
            v1 = fmaf(a1[h], we, v1);
            v2 = fmaf(a2[h], we, v2);
        }
        vs[0][l] = v1; vs[1][l] = v2;
    }
    const float* xb = x + ((size_t)bp * N_ + j0) * C_;
    #pragma unroll
    for (int it = 0; it < 16; ++it)
        xs[it * 4 + w][l] = xb[(it * 4 + w) * C_ + l];
    __syncthreads();

    // partial dot: row j = t>>2, channel quarter t&3; 2-shuffle reduce
    const int jr = t >> 2, c0 = (t & 3) * 16;
    float p1 = 0.f, p2 = 0.f;
    #pragma unroll
    for (int k = 0; k < 16; ++k) {
        float xv = xs[jr][c0 + k];
        p1 = fmaf(xv, vs[0][c0 + k], p1);
        p2 = fmaf(xv, vs[1][c0 + k], p2);
    }
    p1 += __shfl_xor(p1, 1); p1 += __shfl_xor(p1, 2);
    p2 += __shfl_xor(p2, 1); p2 += __shfl_xor(p2, 2);
    if ((l & 3) == 0) {
        s1g[bp * N_ + j0 + jr] = p1;
        s2g[bp * N_ + j0 + jr] = p2;
    }
    float m = p2;
    m = fmaxf(m, __shfl_xor(m, 4));
    m = fmaxf(m, __shfl_xor(m, 8));
    m = fmaxf(m, __shfl_xor(m, 16));
    m = fmaxf(m, __shfl_xor(m, 32));
    if (l == 0) M2part[bp * 64 + blockIdx.x * 4 + w] = m;

    // bf16 transpose out: thread t handles c = t>>2, 16 j's
    const int c = t >> 2, part = t & 3;
    unsigned int ow[8];
    #pragma unroll
    for (int k = 0; k < 16; k += 2) {
        unsigned int lo = f2bf(xs[part * 16 + k][c]);
        unsigned int hi = f2bf(xs[part * 16 + k + 1][c]);
        ow[k >> 1] = lo | (hi << 16);
    }
    uint4* dst = (uint4*)(xT + (size_t)bp * C_ * N_ + (size_t)c * N_ + j0 + part * 16);
    dst[0] = make_uint4(ow[0], ow[1], ow[2], ow[3]);
    dst[1] = make_uint4(ow[4], ow[5], ow[6], ow[7]);
}

// ---------------------------------------------------------------------------
// K2 (fused): A passthrough + mask + softmax + aggregation + W_lin + sigmoid.
// Reads A directly (nontemporal), writes outA (nontemporal) — the copy kernel
// is folded in.  Viable now (vs R1) because the chunk loop has ZERO serial
// cross-lane ops: fixed softmax shift, deferred l-sum, per-wave LDS slices.
// grid (16 i-tiles, 48 bp) = 3 blocks/CU, block 256 = 4 waves x 16 rows.
// ---------------------------------------------------------------------------
__global__ __launch_bounds__(256, 3) void gat_fused(
    const float* __restrict__ Ag, float* __restrict__ outA,
    const unsigned short* __restrict__ xT,
    const float* __restrict__ s1g, const float* __restrict__ s2g,
    const float* __restrict__ M2part,
    const float* __restrict__ Wlin, float* __restrict__ out)
{
    // per-wave P tile: 16 rows x 256 j bf16, row stride 264 ushort (8 pad)
    __shared__ unsigned short Plds[4][16][264];
    const int l = threadIdx.x & 63, w = threadIdx.x >> 6;
    const int i15 = l & 15, q = l >> 4;
    const int bp = blockIdx.y;
    const int ibase = blockIdx.x * 64 + w * 16;

    // reduce per-wave maxima -> M2 (once; 6 shuffles)
    float m2v = M2part[bp * 64 + l];
    #pragma unroll
    for (int off = 32; off >= 1; off >>= 1)
        m2v = fmaxf(m2v, __shfl_xor(m2v, off));
    const float M2 = m2v;

    const float s1_l = s1g[bp * N_ + ibase + i15];   // lane rr holds s1 of row rr
    const float zr = s1_l + M2;
    const float m_l = fmaxf(zr, 0.01f * zr);         // fixed softmax shift

    float s1r[16], mr[16];
    #pragma unroll
    for (int rr = 0; rr < 16; ++rr) {
        s1r[rr] = __shfl(s1_l, rr);
        mr[rr]  = __shfl(m_l, rr);
    }

    const float* Arow = Ag + (size_t)bp * N_ * N_ + (size_t)ibase * N_;
    float* oArow = outA + (size_t)bp * N_ * N_ + (size_t)ibase * N_;
    const unsigned short* xTb = xT + (size_t)bp * C_ * N_;

    f32x4 acc[4] = {};                 // rows q*4+r, c = nt*16+i15
    float lsum[16];
    #pragma unroll
    for (int rr = 0; rr < 16; ++rr) lsum[rr] = 0.f;

    for (int jc = 0; jc < 4; ++jc) {
        const int j0c = jc * 256;
        const f32x4 s2p = *(const f32x4*)&s2g[bp * N_ + j0c + 4 * l];
        f32x4 Ap[16];
        #pragma unroll
        for (int rr = 0; rr < 16; ++rr)   // 16 KB/wave in flight (HBM stream)
            Ap[rr] = __builtin_nontemporal_load(
                (const f32x4*)&Arow[(size_t)rr * N_ + j0c + 4 * l]);
        #pragma unroll
        for (int rr = 0; rr < 16; ++rr) {
            __builtin_nontemporal_store(Ap[rr],
                (f32x4*)&oArow[(size_t)rr * N_ + j0c + 4 * l]);   // A passthrough
            float e[4];
            #pragma unroll
            for (int k = 0; k < 4; ++k) {
                float zz = s1r[rr] + s2p[k];
                zz = fmaxf(zz, 0.01f * zz);                  // leaky_relu
                e[k] = (Ap[rr][k] != 0.f) ? __expf(zz - mr[rr]) : 0.f;
            }
            lsum[rr] += (e[0] + e[1]) + (e[2] + e[3]);
            *(uint2*)&Plds[w][rr][4 * l] =
                make_uint2(pack2(e[0], e[1]), pack2(e[2], e[3]));
        }
        // acc += P_chunk @ X_chunk   (M16 x N64 x K256 per wave)
        #pragma unroll
        for (int s = 0; s < 8; ++s) {
            bf16x8 af = *(const bf16x8*)&Plds[w][i15][s * 32 + q * 8];
            #pragma unroll
            for (int nt = 0; nt < 4; ++nt) {
                bf16x8 bfr = *(const bf16x8*)&xTb[(size_t)(nt * 16 + i15) * N_ +
                                                  j0c + s * 32 + q * 8];
                acc[nt] = __builtin_amdgcn_mfma_f32_16x16x32_bf16(af, bfr, acc[nt], 0, 0, 0);
            }
        }
    }

    // one deferred l-sum reduction per row (16 independent chains)
    #pragma unroll
    for (int rr = 0; rr < 16; ++rr)
        #pragma unroll
        for (int off = 32; off >= 1; off >>= 1)
            lsum[rr] += __shfl_xor(lsum[rr], off);

    // ---- epilogue: agg = acc/l, LDS round-trip to A-layout, @W_lin^T, sigmoid
    unsigned short* aggl = &Plds[w][0][0];   // reuse own P slice, stride 72
    #pragma unroll
    for (int nt = 0; nt < 4; ++nt)
        #pragma unroll
        for (int r = 0; r < 4; ++r) {
            int row = q * 4 + r;
            aggl[row * 72 + nt * 16 + i15] = f2bf(acc[nt][r] / lsum[row]);
        }
    f32x4 d2[4] = {};
    #pragma unroll
    for (int s = 0; s < 2; ++s) {
        bf16x8 af = *(const bf16x8*)&aggl[i15 * 72 + s * 32 + q * 8];
        #pragma unroll
        for (int nt = 0; nt < 4; ++nt) {
            const float* wp = Wlin + (size_t)(nt * 16 + i15) * C_ + s * 32 + q * 8;
            f32x4 w0 = *(const f32x4*)wp;
            f32x4 w1 = *(const f32x4*)(wp + 4);
            bf16x8 bfr;
            #pragma unroll
            for (int jj = 0; jj < 4; ++jj) { bfr[jj] = (__bf16)w0[jj]; bfr[4 + jj] = (__bf16)w1[jj]; }
            d2[nt] = __builtin_amdgcn_mfma_f32_16x16x32_bf16(af, bfr, d2[nt], 0, 0, 0);
        }
    }
    float* orow = out + ((size_t)bp * N_ + ibase) * C_;
    #pragma unroll
    for (int nt = 0; nt < 4; ++nt)
        #pragma unroll
        for (int r = 0; r < 4; ++r)
            orow[(size_t)(q * 4 + r) * C_ + nt * 16 + i15] =
                1.f / (1.f + __expf(-d2[nt][r]));
}

extern "C" void kernel_launch(void* const* d_in, const int* in_sizes, int n_in,
                              void* d_out, int out_size, void* d_ws, size_t ws_size,
                              hipStream_t stream) {
    const float* x    = (const float*)d_in[0];
    const float* Ag   = (const float*)d_in[1];
    const float* Wemb = (const float*)d_in[2];
    const float* a1   = (const float*)d_in[3];
    const float* a2   = (const float*)d_in[4];
    const float* Wlin = (const float*)d_in[5];
    float* out  = (float*)d_out;
    float* outA = out + (size_t)BP_ * N_ * C_;   // tuple output #2: A passthrough

    // ws layout (~6.7 MB total)
    float* s1g = (float*)d_ws;                               // 48K f32
    float* s2g = s1g + BP_ * N_;                             // 48K f32
    float* M2part = s2g + BP_ * N_;                          // 48*64 f32
    unsigned short* xT = (unsigned short*)(M2part + BP_ * 64);   // 6.3MB bf16

    gat_pre<<<dim3(16, BP_), dim3(256), 0, stream>>>(x, Wemb, a1, a2,
                                                     s1g, s2g, xT, M2part);
    gat_fused<<<dim3(16, BP_), dim3(256), 0, stream>>>(Ag, outA, xT, s1g, s2g,
                                                       M2part, Wlin, out);
}